// Round 1
// baseline (115.379 us; speedup 1.0000x reference)
//
#include <hip/hip_runtime.h>

// Pendulum 1-DOF Hamiltonian dynamics, analytic closed form:
//   out[i,0] = p      (= y[i,1])
//   out[i,1] = -G * sin(theta)   (theta = y[i,0]),  G = 9.81
//
// y is [B,2] f32 row-major (interleaved theta,p). One float4 per lane
// processes 2 rows: load (t0,p0,t1,p1), store (p0,-G*sin t0, p1,-G*sin t1).

__global__ __launch_bounds__(256) void pend1dof_kernel(
    const float4* __restrict__ y4, float4* __restrict__ out4, int n4) {
    const float G = 9.81f;
    int idx = blockIdx.x * blockDim.x + threadIdx.x;
    int stride = gridDim.x * blockDim.x;
    for (int i = idx; i < n4; i += stride) {
        float4 v = y4[i];
        float4 r;
        r.x = v.y;
        r.y = -G * sinf(v.x);
        r.z = v.w;
        r.w = -G * sinf(v.z);
        out4[i] = r;
    }
}

extern "C" void kernel_launch(void* const* d_in, const int* in_sizes, int n_in,
                              void* d_out, int out_size, void* d_ws, size_t ws_size,
                              hipStream_t stream) {
    // inputs: d_in[0] = t (1 elem, unused), d_in[1] = y ([B,2] f32)
    const float4* y4 = (const float4*)d_in[1];
    float4* out4 = (float4*)d_out;
    int n_elems = in_sizes[1];          // B*2 floats
    int n4 = n_elems / 4;               // B*2 divisible by 4 (B = 8388608)

    const int block = 256;
    int max_blocks = 256 * 8;           // 256 CUs x 8 blocks/CU
    int blocks = (n4 + block - 1) / block;
    if (blocks > max_blocks) blocks = max_blocks;

    pend1dof_kernel<<<blocks, block, 0, stream>>>(y4, out4, n4);
}